// Round 1
// baseline (388.995 us; speedup 1.0000x reference)
//
#include <hip/hip_runtime.h>
#include <math.h>

#define Bn 512
#define Tn 1024
#define Nn 64
#define LOG2E_F 1.44269504088896340736f
#define LN2_F   0.69314718055994530942f

__device__ __forceinline__ float bcast_lane(float v, int lane) {
    return __int_as_float(__builtin_amdgcn_readlane(__float_as_int(v), lane));
}
__device__ __forceinline__ float wave_max(float v) {
    #pragma unroll
    for (int o = 32; o > 0; o >>= 1) v = fmaxf(v, __shfl_xor(v, o));
    return v;
}
__device__ __forceinline__ float wave_sum(float v) {
    #pragma unroll
    for (int o = 32; o > 0; o >>= 1) v += __shfl_xor(v, o);
    return v;
}

// ---------------------------------------------------------------------------
// Kernel 1: unary + binary scores -> out[b]
// ---------------------------------------------------------------------------
__global__ __launch_bounds__(256) void crf_scores(
    const float* __restrict__ inputs, const float* __restrict__ trans,
    const int* __restrict__ tags, const int* __restrict__ lens,
    float* __restrict__ out)
{
    const int b = blockIdx.x;
    const int L = lens[b];
    const int* tagb = tags + b * Tn;
    const float* inb = inputs + (size_t)b * Tn * Nn;

    float acc = 0.f;
    for (int t = threadIdx.x; t < L; t += 256) {
        int tg = tagb[t];
        acc += inb[t * Nn + tg];
        if (t >= 1) acc += trans[tagb[t - 1] * Nn + tg];
    }
    acc = wave_sum(acc);
    __shared__ float red[4];
    if ((threadIdx.x & 63) == 0) red[threadIdx.x >> 6] = acc;
    __syncthreads();
    if (threadIdx.x == 0) out[b] = (red[0] + red[1]) + (red[2] + red[3]);
}

// ---------------------------------------------------------------------------
// Kernel 2: forward/backward halves of the linear recursion in exp-space.
//   fwd: q' = e^{x_t}/64 (elementwise, lane j) * sum_i q_i E[i][j]
//   bwd: q' = sum_i (e^{x_t}/64 * q)_i E[j][i]   (lane j holds row j)
// Broadcast via v_readlane: no LDS, no barrier, no vmcnt drain in the loop.
// __launch_bounds__(64,1): 1 wave/EU is structural here; give the register
// allocator the full budget so E[64] stays in VGPRs (68-VGPR cap caused
// spill-reload in the loop in R4 -> ~800 stall cyc/step).
// ---------------------------------------------------------------------------

// s_j = sum_i v_i * E[i]  (v broadcast across lanes via readlane)
#define DOT64(vv, dst) do {                                        \
    float _s0 = 0.f, _s1 = 0.f, _s2 = 0.f, _s3 = 0.f;             \
    _Pragma("unroll")                                              \
    for (int _i = 0; _i < 64; _i += 4) {                           \
        _s0 = fmaf(bcast_lane((vv), _i    ), E[_i    ], _s0);      \
        _s1 = fmaf(bcast_lane((vv), _i + 1), E[_i + 1], _s1);      \
        _s2 = fmaf(bcast_lane((vv), _i + 2), E[_i + 2], _s2);      \
        _s3 = fmaf(bcast_lane((vv), _i + 3), E[_i + 3], _s3);      \
    }                                                              \
    (dst) = (_s0 + _s1) + (_s2 + _s3);                             \
} while (0)

// one recursion step; rotates the 4-deep prefetch pipeline
#define STEP(BWDV, kk) do {                                        \
    float _s;                                                      \
    if (BWDV) { float _v = ex * q; DOT64(_v, _s); }                \
    else      { DOT64(q, _s); }                                    \
    xp[0] = xp[1]; xp[1] = xp[2]; xp[2] = xp[3];                   \
    if ((kk) + 4 < n) xp[3] = inb[(t + 4 * dir) * Nn + j];         \
    float _exn = exp2f(fmaf(xp[0], LOG2E_F, -6.0f));               \
    q = (BWDV) ? _s : ex * _s;                                     \
    ex = _exn; t += dir;                                           \
} while (0)

#define RENORM() do {                                              \
    float _m = wave_max(q);                                        \
    q *= (1.0f / _m);                                              \
    base += __logf(_m);                                            \
} while (0)

template <bool FULL>
__global__ __launch_bounds__(64, 1) void crf_fwdbwd(
    const float* __restrict__ inputs, const float* __restrict__ trans,
    const int* __restrict__ lens, float* __restrict__ ws,
    float* __restrict__ out)
{
    const int j = threadIdx.x;
    const bool bwd = (!FULL) && (blockIdx.x >= Bn);
    const int b = bwd ? (blockIdx.x - Bn) : blockIdx.x;
    const int L = lens[b];
    const float* inb = inputs + (size_t)b * Tn * Nn;

    // E in registers: fwd lane j holds column j (E[i][j]) -- coalesced direct;
    // bwd lane j holds row j (E[j][i]) -- transpose via LDS (setup only).
    float E[64];
    __shared__ float trsh[64 * 65];
    if (!bwd) {
        #pragma unroll
        for (int i = 0; i < 64; ++i) E[i] = exp2f(trans[i * 64 + j] * LOG2E_F);
    } else {
        #pragma unroll
        for (int i = 0; i < 64; ++i) trsh[i * 65 + j] = trans[i * 64 + j];
        __syncthreads();
        #pragma unroll
        for (int i = 0; i < 64; ++i) E[i] = exp2f(trsh[j * 65 + i] * LOG2E_F);
    }

    float q, base;
    int t0, dir, n;
    const int tf = L >> 1;           // forward covers t in [1,tf], backward (tf, L-1]
    if (!bwd) {
        float x0 = inb[j];
        float m = wave_max(x0);
        q = exp2f((x0 - m) * LOG2E_F);
        base = m;
        t0 = 1; dir = 1;
        n = FULL ? (L - 1) : tf;
    } else {
        q = 1.f; base = 0.f;
        t0 = L - 1; dir = -1;
        n = (L - 1) - tf;
    }

    // 4-deep register prefetch pipeline for x rows
    float xp[4];
    #pragma unroll
    for (int d = 0; d < 4; ++d) xp[d] = (d < n) ? inb[(t0 + d * dir) * Nn + j] : 0.f;

    int t = t0;
    float ex = exp2f(fmaf(xp[0], LOG2E_F, -6.0f));  // e^x / 64, one step ahead

    int k = 0;
    if (!bwd) {
        while (k + 8 <= n) {
            #pragma unroll
            for (int u = 0; u < 8; ++u) STEP(false, k + u);
            k += 8;
            RENORM();
        }
        while (k < n) { STEP(false, k); ++k; }
    } else {
        while (k + 8 <= n) {
            #pragma unroll
            for (int u = 0; u < 8; ++u) STEP(true, k + u);
            k += 8;
            RENORM();
        }
        while (k < n) { STEP(true, k); ++k; }
    }

    // final renorm + account for the per-step 1/64 scaling
    {
        float m = wave_max(q);
        q *= (1.0f / m);
        base += __logf(m) + LN2_F * 6.0f * (float)n;
    }

    if (FULL) {
        float ssum = wave_sum(q);
        if (j == 0) out[b] -= (base + __logf(ssum));
    } else {
        float* fvec = ws;
        float* gvec = ws + Bn * 64;
        float* fb   = ws + 2 * Bn * 64;
        float* gb   = fb + Bn;
        if (!bwd) { fvec[b * 64 + j] = q; if (j == 0) fb[b] = base; }
        else      { gvec[b * 64 + j] = q; if (j == 0) gb[b] = base; }
    }
}

// ---------------------------------------------------------------------------
// Kernel 3: combine halves: logZ = log(f . g) + fbase + gbase; out[b] -= logZ
// ---------------------------------------------------------------------------
__global__ __launch_bounds__(64, 1) void crf_combine(
    const float* __restrict__ ws, float* __restrict__ out)
{
    const int b = blockIdx.x;
    const int j = threadIdx.x;
    const float* fvec = ws;
    const float* gvec = ws + Bn * 64;
    const float* fb   = ws + 2 * Bn * 64;
    const float* gb   = fb + Bn;

    float p = wave_sum(fvec[b * 64 + j] * gvec[b * 64 + j]);
    if (j == 0) out[b] -= (__logf(p) + fb[b] + gb[b]);
}

extern "C" void kernel_launch(void* const* d_in, const int* in_sizes, int n_in,
                              void* d_out, int out_size, void* d_ws, size_t ws_size,
                              hipStream_t stream) {
    const float* inputs = (const float*)d_in[0];
    const float* trans  = (const float*)d_in[1];
    const int*   tags   = (const int*)d_in[2];
    const int*   lens   = (const int*)d_in[3];
    float* out = (float*)d_out;
    float* ws  = (float*)d_ws;

    crf_scores<<<Bn, 256, 0, stream>>>(inputs, trans, tags, lens, out);

    const size_t need = (size_t)(2 * Bn * 64 + 2 * Bn) * sizeof(float);
    if (ws_size >= need) {
        crf_fwdbwd<false><<<2 * Bn, 64, 0, stream>>>(inputs, trans, lens, ws, out);
        crf_combine<<<Bn, 64, 0, stream>>>(ws, out);
    } else {
        // workspace too small: single-direction fallback (slower, no ws needed)
        crf_fwdbwd<true><<<Bn, 64, 0, stream>>>(inputs, trans, lens, ws, out);
    }
}

// Round 2
// 378.857 us; speedup vs baseline: 1.0268x; 1.0268x over previous
//
#include <hip/hip_runtime.h>
#include <math.h>

#define Bn 512
#define Tn 1024
#define Nn 64
#define LOG2E_F 1.44269504088896340736f
#define LN2_F   0.69314718055994530942f
#define PF 6

__device__ __forceinline__ float wave_max(float v) {
    #pragma unroll
    for (int o = 32; o > 0; o >>= 1) v = fmaxf(v, __shfl_xor(v, o));
    return v;
}
__device__ __forceinline__ float wave_sum(float v) {
    #pragma unroll
    for (int o = 32; o > 0; o >>= 1) v += __shfl_xor(v, o);
    return v;
}

// ---------------------------------------------------------------------------
// Kernel 1: unary + binary scores -> out[b]
// ---------------------------------------------------------------------------
__global__ __launch_bounds__(256) void crf_scores(
    const float* __restrict__ inputs, const float* __restrict__ trans,
    const int* __restrict__ tags, const int* __restrict__ lens,
    float* __restrict__ out)
{
    const int b = blockIdx.x;
    const int L = lens[b];
    const int* tagb = tags + b * Tn;
    const float* inb = inputs + (size_t)b * Tn * Nn;

    float acc = 0.f;
    for (int t = threadIdx.x; t < L; t += 256) {
        int tg = tagb[t];
        acc += inb[t * Nn + tg];
        if (t >= 1) acc += trans[tagb[t - 1] * Nn + tg];
    }
    acc = wave_sum(acc);
    __shared__ float red[4];
    if ((threadIdx.x & 63) == 0) red[threadIdx.x >> 6] = acc;
    __syncthreads();
    if (threadIdx.x == 0) out[b] = (red[0] + red[1]) + (red[2] + red[3]);
}

// ---------------------------------------------------------------------------
// Kernel 2: forward/backward halves of the linear recursion in exp-space.
//   fwd: q' = e^{x_t}/64 (elementwise, lane j) * sum_i q_i E[i][j]
//   bwd: q' = sum_i (e^{x_t}/64 * q)_i E[j][i]   (lane j holds row j)
//
// R1 fix: broadcast of q across lanes now goes through LDS same-address
// ds_read_b128 (hardware broadcast path, conflict-free) instead of 64
// v_readlane -> SGPR -> v_fma pairs. R1 counters showed VALUBusy=28% with
// ~740 stall cyc/step from the SGPR write->read hazard fully exposed at
// 1 wave/SIMD. The LDS path keeps broadcast values in VGPRs (no SGPR
// hazard); write-at-step-start means renorm never rewrites LDS.
// ---------------------------------------------------------------------------

// s_j = sum_i shq[i] * E[i]   (shq uniform-address float4 broadcast reads)
#define DOT_LDS(dst) do {                                          \
    float _s0 = 0.f, _s1 = 0.f, _s2 = 0.f, _s3 = 0.f;             \
    _Pragma("unroll")                                              \
    for (int _i = 0; _i < 64; _i += 4) {                           \
        float4 _qv = *(const float4*)&shq[_i];                     \
        _s0 = fmaf(_qv.x, E[_i    ], _s0);                         \
        _s1 = fmaf(_qv.y, E[_i + 1], _s1);                         \
        _s2 = fmaf(_qv.z, E[_i + 2], _s2);                         \
        _s3 = fmaf(_qv.w, E[_i + 3], _s3);                         \
    }                                                              \
    (dst) = (_s0 + _s1) + (_s2 + _s3);                             \
} while (0)

// one recursion step; writes the broadcast vector first, then dots it.
// in-order per-wave LDS queue: write(k) is processed before reads(k), and
// reads(k) before write(k+1) -- no barrier needed (single wave).
#define STEP(BWDV, kk) do {                                        \
    float _v = (BWDV) ? (ex * q) : q;                              \
    shq[j] = _v;                                                   \
    float _s; DOT_LDS(_s);                                         \
    _Pragma("unroll")                                              \
    for (int _d = 0; _d < PF - 1; ++_d) xp[_d] = xp[_d + 1];       \
    if ((kk) + PF < n) xp[PF - 1] = inb[(t + PF * dir) * Nn + j];  \
    float _exn = exp2f(fmaf(xp[0], LOG2E_F, -6.0f));               \
    q = (BWDV) ? _s : (ex * _s);                                   \
    ex = _exn; t += dir;                                           \
} while (0)

#define RENORM() do {                                              \
    float _m = wave_max(q);                                        \
    q *= (1.0f / _m);                                              \
    base += __logf(_m);                                            \
} while (0)

template <bool FULL>
__global__ __launch_bounds__(64, 1) void crf_fwdbwd(
    const float* __restrict__ inputs, const float* __restrict__ trans,
    const int* __restrict__ lens, float* __restrict__ ws,
    float* __restrict__ out)
{
    const int j = threadIdx.x;
    const bool bwd = (!FULL) && (blockIdx.x >= Bn);
    const int b = bwd ? (blockIdx.x - Bn) : blockIdx.x;
    const int L = lens[b];
    const float* inb = inputs + (size_t)b * Tn * Nn;

    // E in registers: fwd lane j holds column j (E[i][j]) -- coalesced direct;
    // bwd lane j holds row j (E[j][i]) -- transpose via LDS (setup only).
    float E[64];
    __shared__ float trsh[64 * 65];
    __shared__ __align__(16) float shq[64];
    if (!bwd) {
        #pragma unroll
        for (int i = 0; i < 64; ++i) E[i] = exp2f(trans[i * 64 + j] * LOG2E_F);
    } else {
        #pragma unroll
        for (int i = 0; i < 64; ++i) trsh[i * 65 + j] = trans[i * 64 + j];
        __syncthreads();
        #pragma unroll
        for (int i = 0; i < 64; ++i) E[i] = exp2f(trsh[j * 65 + i] * LOG2E_F);
    }

    float q, base;
    int t0, dir, n;
    const int tf = L >> 1;           // forward covers t in [1,tf], backward (tf, L-1]
    if (!bwd) {
        float x0 = inb[j];
        float m = wave_max(x0);
        q = exp2f((x0 - m) * LOG2E_F);
        base = m;
        t0 = 1; dir = 1;
        n = FULL ? (L - 1) : tf;
    } else {
        q = 1.f; base = 0.f;
        t0 = L - 1; dir = -1;
        n = (L - 1) - tf;
    }

    // PF-deep register prefetch pipeline for x rows (covers L3/HBM latency
    // now that the step shrank to ~200 cyc)
    float xp[PF];
    #pragma unroll
    for (int d = 0; d < PF; ++d) xp[d] = (d < n) ? inb[(t0 + d * dir) * Nn + j] : 0.f;

    int t = t0;
    float ex = exp2f(fmaf(xp[0], LOG2E_F, -6.0f));  // e^x / 64, one step ahead

    int k = 0;
    if (!bwd) {
        while (k + 8 <= n) {
            #pragma unroll
            for (int u = 0; u < 8; ++u) STEP(false, k + u);
            k += 8;
            RENORM();
        }
        while (k < n) { STEP(false, k); ++k; }
    } else {
        while (k + 8 <= n) {
            #pragma unroll
            for (int u = 0; u < 8; ++u) STEP(true, k + u);
            k += 8;
            RENORM();
        }
        while (k < n) { STEP(true, k); ++k; }
    }

    // final renorm + account for the per-step 1/64 scaling
    {
        float m = wave_max(q);
        q *= (1.0f / m);
        base += __logf(m) + LN2_F * 6.0f * (float)n;
    }

    if (FULL) {
        float ssum = wave_sum(q);
        if (j == 0) out[b] -= (base + __logf(ssum));
    } else {
        float* fvec = ws;
        float* gvec = ws + Bn * 64;
        float* fb   = ws + 2 * Bn * 64;
        float* gb   = fb + Bn;
        if (!bwd) { fvec[b * 64 + j] = q; if (j == 0) fb[b] = base; }
        else      { gvec[b * 64 + j] = q; if (j == 0) gb[b] = base; }
    }
}

// ---------------------------------------------------------------------------
// Kernel 3: combine halves: logZ = log(f . g) + fbase + gbase; out[b] -= logZ
// ---------------------------------------------------------------------------
__global__ __launch_bounds__(64, 1) void crf_combine(
    const float* __restrict__ ws, float* __restrict__ out)
{
    const int b = blockIdx.x;
    const int j = threadIdx.x;
    const float* fvec = ws;
    const float* gvec = ws + Bn * 64;
    const float* fb   = ws + 2 * Bn * 64;
    const float* gb   = fb + Bn;

    float p = wave_sum(fvec[b * 64 + j] * gvec[b * 64 + j]);
    if (j == 0) out[b] -= (__logf(p) + fb[b] + gb[b]);
}

extern "C" void kernel_launch(void* const* d_in, const int* in_sizes, int n_in,
                              void* d_out, int out_size, void* d_ws, size_t ws_size,
                              hipStream_t stream) {
    const float* inputs = (const float*)d_in[0];
    const float* trans  = (const float*)d_in[1];
    const int*   tags   = (const int*)d_in[2];
    const int*   lens   = (const int*)d_in[3];
    float* out = (float*)d_out;
    float* ws  = (float*)d_ws;

    crf_scores<<<Bn, 256, 0, stream>>>(inputs, trans, tags, lens, out);

    const size_t need = (size_t)(2 * Bn * 64 + 2 * Bn) * sizeof(float);
    if (ws_size >= need) {
        crf_fwdbwd<false><<<2 * Bn, 64, 0, stream>>>(inputs, trans, lens, ws, out);
        crf_combine<<<Bn, 64, 0, stream>>>(ws, out);
    } else {
        // workspace too small: single-direction fallback (slower, no ws needed)
        crf_fwdbwd<true><<<Bn, 64, 0, stream>>>(inputs, trans, lens, ws, out);
    }
}

// Round 3
// 355.437 us; speedup vs baseline: 1.0944x; 1.0659x over previous
//
#include <hip/hip_runtime.h>
#include <math.h>

#define Bn 512
#define Tn 1024
#define Nn 64
#define LOG2E_F 1.44269504088896340736f
#define LN2_F   0.69314718055994530942f

__device__ __forceinline__ float wave_max(float v) {
    #pragma unroll
    for (int o = 32; o > 0; o >>= 1) v = fmaxf(v, __shfl_xor(v, o));
    return v;
}
__device__ __forceinline__ float wave_sum(float v) {
    #pragma unroll
    for (int o = 32; o > 0; o >>= 1) v += __shfl_xor(v, o);
    return v;
}

// ---------------------------------------------------------------------------
// Kernel 1: unary + binary scores -> out[b]
// ---------------------------------------------------------------------------
__global__ __launch_bounds__(256) void crf_scores(
    const float* __restrict__ inputs, const float* __restrict__ trans,
    const int* __restrict__ tags, const int* __restrict__ lens,
    float* __restrict__ out)
{
    const int b = blockIdx.x;
    const int L = lens[b];
    const int* tagb = tags + b * Tn;
    const float* inb = inputs + (size_t)b * Tn * Nn;

    float acc = 0.f;
    for (int t = threadIdx.x; t < L; t += 256) {
        int tg = tagb[t];
        acc += inb[t * Nn + tg];
        if (t >= 1) acc += trans[tagb[t - 1] * Nn + tg];
    }
    acc = wave_sum(acc);
    __shared__ float red[4];
    if ((threadIdx.x & 63) == 0) red[threadIdx.x >> 6] = acc;
    __syncthreads();
    if (threadIdx.x == 0) out[b] = (red[0] + red[1]) + (red[2] + red[3]);
}

// ---------------------------------------------------------------------------
// Kernel 2: forward/backward halves of the linear recursion in exp-space.
//   fwd: q' = e^{x_t}/64 (elementwise, lane j) * sum_i q_i E[i][j]
//   bwd: q' = sum_i (e^{x_t}/64 * q)_i E[j][i]   (lane j holds row j)
//
// R2 post-mortem: R1 (readlane dot) and R2 (LDS-broadcast dot) both ran at
// ~1060 cyc/step -> the stall was never VALU-side; it is the CONDITIONAL
// prefetch load (`if (k+PF < n)`), which makes outstanding-load count
// statically unknowable and forces a vmcnt(0) drain (~700 cyc L3 latency)
// every step. R3 fix: 8-step supersteps; next 8 rows loaded UNCONDITIONALLY
// (row index clamped to [0, L-1] instead of skipped) into a double buffer.
// Loads are now statically countable; wait amortizes over 8 steps.
// ---------------------------------------------------------------------------

// s_j = sum_i shq[i] * E[i]   (shq uniform-address float4 broadcast reads)
#define DOT_LDS(dst) do {                                          \
    float _s0 = 0.f, _s1 = 0.f, _s2 = 0.f, _s3 = 0.f;             \
    _Pragma("unroll")                                              \
    for (int _i = 0; _i < 64; _i += 4) {                           \
        float4 _qv = *(const float4*)&shq[_i];                     \
        _s0 = fmaf(_qv.x, E[_i    ], _s0);                         \
        _s1 = fmaf(_qv.y, E[_i + 1], _s1);                         \
        _s2 = fmaf(_qv.z, E[_i + 2], _s2);                         \
        _s3 = fmaf(_qv.w, E[_i + 3], _s3);                         \
    }                                                              \
    (dst) = (_s0 + _s1) + (_s2 + _s3);                             \
} while (0)

// one recursion step. single wave: LDS queue is in-order per wave, so
// write(k) -> reads(k) -> write(k+1) needs no barrier.
#define STEPX(BWDV, EXV) do {                                      \
    shq[j] = (BWDV) ? ((EXV) * q) : q;                             \
    float _s; DOT_LDS(_s);                                         \
    q = (BWDV) ? _s : ((EXV) * _s);                                \
} while (0)

#define RENORM() do {                                              \
    float _m = wave_max(q);                                        \
    q *= (1.0f / _m);                                              \
    base += __logf(_m);                                            \
} while (0)

// clamped row index: keeps every prefetch load unconditional + in-bounds
__device__ __forceinline__ int clamp_row(int tt, int Lm1) {
    return tt < 0 ? 0 : (tt > Lm1 ? Lm1 : tt);
}

template <bool FULL>
__global__ __launch_bounds__(64, 1) void crf_fwdbwd(
    const float* __restrict__ inputs, const float* __restrict__ trans,
    const int* __restrict__ lens, float* __restrict__ ws,
    float* __restrict__ out)
{
    const int j = threadIdx.x;
    const bool bwd = (!FULL) && (blockIdx.x >= Bn);
    const int b = bwd ? (blockIdx.x - Bn) : blockIdx.x;
    const int L = lens[b];
    const int Lm1 = L - 1;
    const float* inb = inputs + (size_t)b * Tn * Nn;

    // E in registers: fwd lane j holds column j (E[i][j]) -- coalesced direct;
    // bwd lane j holds row j (E[j][i]) -- transpose via LDS (setup only).
    float E[64];
    __shared__ float trsh[64 * 65];
    __shared__ __align__(16) float shq[64];
    if (!bwd) {
        #pragma unroll
        for (int i = 0; i < 64; ++i) E[i] = exp2f(trans[i * 64 + j] * LOG2E_F);
    } else {
        #pragma unroll
        for (int i = 0; i < 64; ++i) trsh[i * 65 + j] = trans[i * 64 + j];
        __syncthreads();
        #pragma unroll
        for (int i = 0; i < 64; ++i) E[i] = exp2f(trsh[j * 65 + i] * LOG2E_F);
    }

    float q, base;
    int t0, dir, n;
    const int tf = L >> 1;           // forward covers t in [1,tf], backward (tf, L-1]
    if (!bwd) {
        float x0 = inb[j];
        float m = wave_max(x0);
        q = exp2f((x0 - m) * LOG2E_F);
        base = m;
        t0 = 1; dir = 1;
        n = FULL ? (L - 1) : tf;
    } else {
        q = 1.f; base = 0.f;
        t0 = L - 1; dir = -1;
        n = (L - 1) - tf;
    }

    // current 8-row register buffer (unconditional clamped loads)
    float xc[8];
    #pragma unroll
    for (int d = 0; d < 8; ++d)
        xc[d] = inb[clamp_row(t0 + d * dir, Lm1) * Nn + j];

    int t = t0;
    int k = 0;
    if (!bwd) {
        while (k + 8 <= n) {
            float xn[8];
            #pragma unroll
            for (int d = 0; d < 8; ++d)
                xn[d] = inb[clamp_row(t + (8 + d) * dir, Lm1) * Nn + j];
            #pragma unroll
            for (int u = 0; u < 8; ++u) {
                float exu = exp2f(fmaf(xc[u], LOG2E_F, -6.0f));
                STEPX(false, exu);
            }
            RENORM();
            #pragma unroll
            for (int d = 0; d < 8; ++d) xc[d] = xn[d];
            k += 8; t += 8;
        }
        #pragma unroll
        for (int u = 0; u < 8; ++u) {
            if (k + u < n) {
                float exu = exp2f(fmaf(xc[u], LOG2E_F, -6.0f));
                STEPX(false, exu);
            }
        }
    } else {
        while (k + 8 <= n) {
            float xn[8];
            #pragma unroll
            for (int d = 0; d < 8; ++d)
                xn[d] = inb[clamp_row(t - (8 + d), Lm1) * Nn + j];
            #pragma unroll
            for (int u = 0; u < 8; ++u) {
                float exu = exp2f(fmaf(xc[u], LOG2E_F, -6.0f));
                STEPX(true, exu);
            }
            RENORM();
            #pragma unroll
            for (int d = 0; d < 8; ++d) xc[d] = xn[d];
            k += 8; t -= 8;
        }
        #pragma unroll
        for (int u = 0; u < 8; ++u) {
            if (k + u < n) {
                float exu = exp2f(fmaf(xc[u], LOG2E_F, -6.0f));
                STEPX(true, exu);
            }
        }
    }

    // final renorm + account for the per-step 1/64 scaling
    {
        float m = wave_max(q);
        q *= (1.0f / m);
        base += __logf(m) + LN2_F * 6.0f * (float)n;
    }

    if (FULL) {
        float ssum = wave_sum(q);
        if (j == 0) out[b] -= (base + __logf(ssum));
    } else {
        float* fvec = ws;
        float* gvec = ws + Bn * 64;
        float* fb   = ws + 2 * Bn * 64;
        float* gb   = fb + Bn;
        if (!bwd) { fvec[b * 64 + j] = q; if (j == 0) fb[b] = base; }
        else      { gvec[b * 64 + j] = q; if (j == 0) gb[b] = base; }
    }
}

// ---------------------------------------------------------------------------
// Kernel 3: combine halves: logZ = log(f . g) + fbase + gbase; out[b] -= logZ
// ---------------------------------------------------------------------------
__global__ __launch_bounds__(64, 1) void crf_combine(
    const float* __restrict__ ws, float* __restrict__ out)
{
    const int b = blockIdx.x;
    const int j = threadIdx.x;
    const float* fvec = ws;
    const float* gvec = ws + Bn * 64;
    const float* fb   = ws + 2 * Bn * 64;
    const float* gb   = fb + Bn;

    float p = wave_sum(fvec[b * 64 + j] * gvec[b * 64 + j]);
    if (j == 0) out[b] -= (__logf(p) + fb[b] + gb[b]);
}

extern "C" void kernel_launch(void* const* d_in, const int* in_sizes, int n_in,
                              void* d_out, int out_size, void* d_ws, size_t ws_size,
                              hipStream_t stream) {
    const float* inputs = (const float*)d_in[0];
    const float* trans  = (const float*)d_in[1];
    const int*   tags   = (const int*)d_in[2];
    const int*   lens   = (const int*)d_in[3];
    float* out = (float*)d_out;
    float* ws  = (float*)d_ws;

    crf_scores<<<Bn, 256, 0, stream>>>(inputs, trans, tags, lens, out);

    const size_t need = (size_t)(2 * Bn * 64 + 2 * Bn) * sizeof(float);
    if (ws_size >= need) {
        crf_fwdbwd<false><<<2 * Bn, 64, 0, stream>>>(inputs, trans, lens, ws, out);
        crf_combine<<<Bn, 64, 0, stream>>>(ws, out);
    } else {
        // workspace too small: single-direction fallback (slower, no ws needed)
        crf_fwdbwd<true><<<Bn, 64, 0, stream>>>(inputs, trans, lens, ws, out);
    }
}

// Round 4
// 313.067 us; speedup vs baseline: 1.2425x; 1.1353x over previous
//
#include <hip/hip_runtime.h>
#include <math.h>

#define Bn 512
#define Tn 1024
#define Nn 64
#define LOG2E_F 1.44269504088896340736f
#define LN2_F   0.69314718055994530942f

__device__ __forceinline__ float wave_max(float v) {
    #pragma unroll
    for (int o = 32; o > 0; o >>= 1) v = fmaxf(v, __shfl_xor(v, o));
    return v;
}
__device__ __forceinline__ float wave_sum(float v) {
    #pragma unroll
    for (int o = 32; o > 0; o >>= 1) v += __shfl_xor(v, o);
    return v;
}

// ---------------------------------------------------------------------------
// Kernel 1: unary + binary scores -> out[b]
// ---------------------------------------------------------------------------
__global__ __launch_bounds__(256) void crf_scores(
    const float* __restrict__ inputs, const float* __restrict__ trans,
    const int* __restrict__ tags, const int* __restrict__ lens,
    float* __restrict__ out)
{
    const int b = blockIdx.x;
    const int L = lens[b];
    const int* tagb = tags + b * Tn;
    const float* inb = inputs + (size_t)b * Tn * Nn;

    float acc = 0.f;
    for (int t = threadIdx.x; t < L; t += 256) {
        int tg = tagb[t];
        acc += inb[t * Nn + tg];
        if (t >= 1) acc += trans[tagb[t - 1] * Nn + tg];
    }
    acc = wave_sum(acc);
    __shared__ float red[4];
    if ((threadIdx.x & 63) == 0) red[threadIdx.x >> 6] = acc;
    __syncthreads();
    if (threadIdx.x == 0) out[b] = (red[0] + red[1]) + (red[2] + red[3]);
}

// ---------------------------------------------------------------------------
// Kernel 2: forward/backward halves of the linear recursion in exp-space.
//   fwd: q'_o = ex_o * sum_i q_i E[i][o]
//   bwd: q'_o = sum_i (ex*q)_i E[o][i]
//
// R4 structure (R1/R2/R3 measured the serial chain at ~886-1060 cyc/step,
// invariant across readlane vs LDS-broadcast dots -> LDS round-trip bound):
//  - 2-way K-split dot: lane (g=j>>5, p=j&31) reads ONLY its input half of q
//    (8 ds_read_b128, 2 addrs/instr = 2-way bank alias = free) and
//    accumulates partials for outputs {p, p+32}; one shfl_xor(32) + add
//    completes both dots. LDS pipe ops/step: 17 -> 9 (+1 shfl).
//  - deferred renorm: wave_max (6 dependent ds_swizzle, ~600 cyc) is
//    measured at superstep end but 1/m is applied 2 steps into the NEXT
//    superstep (folded into exc[2], off the serial chain). Recursion is
//    linear so late scaling is exact; 10-step drift bounded ~e^18, safe.
//  - ex precomputed per superstep (off-chain); loads stay unconditional
//    clamped (R3).
// ---------------------------------------------------------------------------

// one recursion step; exact fp32. Single wave: LDS queue is in-order per
// wave, so write -> reads needs no barrier.
#define STEP2(BWDV, EXV) do {                                      \
    shq[j] = (BWDV) ? ((EXV) * q) : q;                             \
    float4 _qv[8];                                                 \
    _Pragma("unroll")                                              \
    for (int _cb = 0; _cb < 8; ++_cb)                              \
        _qv[_cb] = *(const float4*)&shq[(g << 5) + (_cb << 2)];    \
    float _aP0 = 0.f, _aP1 = 0.f, _aQ0 = 0.f, _aQ1 = 0.f;         \
    _Pragma("unroll")                                              \
    for (int _cb = 0; _cb < 8; _cb += 2) {                         \
        const float4 _u0 = _qv[_cb], _u1 = _qv[_cb + 1];           \
        _aP0 = fmaf(_u0.x, Ef[4*_cb + 0], _aP0);                   \
        _aQ0 = fmaf(_u0.x, Ef[32 + 4*_cb + 0], _aQ0);              \
        _aP0 = fmaf(_u0.y, Ef[4*_cb + 1], _aP0);                   \
        _aQ0 = fmaf(_u0.y, Ef[32 + 4*_cb + 1], _aQ0);              \
        _aP0 = fmaf(_u0.z, Ef[4*_cb + 2], _aP0);                   \
        _aQ0 = fmaf(_u0.z, Ef[32 + 4*_cb + 2], _aQ0);              \
        _aP0 = fmaf(_u0.w, Ef[4*_cb + 3], _aP0);                   \
        _aQ0 = fmaf(_u0.w, Ef[32 + 4*_cb + 3], _aQ0);              \
        _aP1 = fmaf(_u1.x, Ef[4*_cb + 4], _aP1);                   \
        _aQ1 = fmaf(_u1.x, Ef[32 + 4*_cb + 4], _aQ1);              \
        _aP1 = fmaf(_u1.y, Ef[4*_cb + 5], _aP1);                   \
        _aQ1 = fmaf(_u1.y, Ef[32 + 4*_cb + 5], _aQ1);              \
        _aP1 = fmaf(_u1.z, Ef[4*_cb + 6], _aP1);                   \
        _aQ1 = fmaf(_u1.z, Ef[32 + 4*_cb + 6], _aQ1);              \
        _aP1 = fmaf(_u1.w, Ef[4*_cb + 7], _aP1);                   \
        _aQ1 = fmaf(_u1.w, Ef[32 + 4*_cb + 7], _aQ1);              \
    }                                                              \
    float _aP = _aP0 + _aP1, _aQ = _aQ0 + _aQ1;                    \
    float _u = lo32 ? _aP : _aQ;                                   \
    float _w = lo32 ? _aQ : _aP;                                   \
    float _s = _u + __shfl_xor(_w, 32);                            \
    q = (BWDV) ? _s : ((EXV) * _s);                                \
} while (0)

// clamped row index: keeps every prefetch load unconditional + in-bounds
__device__ __forceinline__ int clamp_row(int tt, int Lm1) {
    return tt < 0 ? 0 : (tt > Lm1 ? Lm1 : tt);
}

template <bool FULL>
__global__ __launch_bounds__(64, 1) void crf_fwdbwd(
    const float* __restrict__ inputs, const float* __restrict__ trans,
    const int* __restrict__ lens, float* __restrict__ ws,
    float* __restrict__ out)
{
    const int j = threadIdx.x;
    const int g = j >> 5;            // input K-half this lane reads
    const int p = j & 31;
    const bool lo32 = (j < 32);
    const bool bwd = (!FULL) && (blockIdx.x >= Bn);
    const int b = bwd ? (blockIdx.x - Bn) : blockIdx.x;
    const int L = lens[b];
    const int Lm1 = L - 1;
    const float* inb = inputs + (size_t)b * Tn * Nn;

    // Ef[c]    : weight of input (g*32+c) -> output p
    // Ef[32+c] : weight of input (g*32+c) -> output p+32
    float Ef[64];
    __shared__ float trsh[64 * 65];
    __shared__ __align__(16) float shq[64];
    if (!bwd) {
        // fwd: E[i][o] = exp(trans[i*64+o])
        #pragma unroll
        for (int c = 0; c < 32; ++c) {
            Ef[c]      = exp2f(trans[(g * 32 + c) * 64 + p     ] * LOG2E_F);
            Ef[32 + c] = exp2f(trans[(g * 32 + c) * 64 + p + 32] * LOG2E_F);
        }
    } else {
        // bwd: E[o][i] = exp(trans[o*64+i]); transpose-gather via LDS
        #pragma unroll
        for (int i = 0; i < 64; ++i) trsh[i * 65 + j] = trans[i * 64 + j];
        __syncthreads();
        #pragma unroll
        for (int c = 0; c < 32; ++c) {
            Ef[c]      = exp2f(trsh[p        * 65 + g * 32 + c] * LOG2E_F);
            Ef[32 + c] = exp2f(trsh[(p + 32) * 65 + g * 32 + c] * LOG2E_F);
        }
    }

    float q, base;
    int t0, dir, n;
    const int tf = L >> 1;           // forward covers t in [1,tf], backward (tf, L-1]
    if (!bwd) {
        float x0 = inb[j];
        float m = wave_max(x0);
        q = exp2f((x0 - m) * LOG2E_F);
        base = m;
        t0 = 1; dir = 1;
        n = FULL ? (L - 1) : tf;
    } else {
        q = 1.f; base = 0.f;
        t0 = L - 1; dir = -1;
        n = (L - 1) - tf;
    }

    // current 8-row register buffer (unconditional clamped loads)
    float xc[8];
    #pragma unroll
    for (int d = 0; d < 8; ++d)
        xc[d] = inb[clamp_row(t0 + d * dir, Lm1) * Nn + j];

    int t = t0;
    int k = 0;
    float pend = 1.0f;               // deferred 1/m from previous superstep

    if (!bwd) {
        while (k + 8 <= n) {
            float xn[8];
            #pragma unroll
            for (int d = 0; d < 8; ++d)
                xn[d] = inb[clamp_row(t + (8 + d) * dir, Lm1) * Nn + j];
            float exc[8];
            #pragma unroll
            for (int u = 0; u < 8; ++u)
                exc[u] = exp2f(fmaf(xc[u], LOG2E_F, -6.0f));
            exc[2] *= pend;          // apply deferred renorm off the chain
            #pragma unroll
            for (int u = 0; u < 8; ++u) STEP2(false, exc[u]);
            float m = wave_max(q);   // latency hides under next superstep
            base += __logf(m);
            pend = 1.0f / m;
            #pragma unroll
            for (int d = 0; d < 8; ++d) xc[d] = xn[d];
            k += 8; t += 8;
        }
        q *= pend; pend = 1.0f;
        #pragma unroll
        for (int u = 0; u < 8; ++u) {
            if (k + u < n) {
                float exu = exp2f(fmaf(xc[u], LOG2E_F, -6.0f));
                STEP2(false, exu);
            }
        }
    } else {
        while (k + 8 <= n) {
            float xn[8];
            #pragma unroll
            for (int d = 0; d < 8; ++d)
                xn[d] = inb[clamp_row(t - (8 + d), Lm1) * Nn + j];
            float exc[8];
            #pragma unroll
            for (int u = 0; u < 8; ++u)
                exc[u] = exp2f(fmaf(xc[u], LOG2E_F, -6.0f));
            exc[2] *= pend;
            #pragma unroll
            for (int u = 0; u < 8; ++u) STEP2(true, exc[u]);
            float m = wave_max(q);
            base += __logf(m);
            pend = 1.0f / m;
            #pragma unroll
            for (int d = 0; d < 8; ++d) xc[d] = xn[d];
            k += 8; t -= 8;
        }
        q *= pend; pend = 1.0f;
        #pragma unroll
        for (int u = 0; u < 8; ++u) {
            if (k + u < n) {
                float exu = exp2f(fmaf(xc[u], LOG2E_F, -6.0f));
                STEP2(true, exu);
            }
        }
    }

    // final renorm + account for the per-step 1/64 scaling
    {
        float m = wave_max(q);
        q *= (1.0f / m);
        base += __logf(m) + LN2_F * 6.0f * (float)n;
    }

    if (FULL) {
        float ssum = wave_sum(q);
        if (j == 0) out[b] -= (base + __logf(ssum));
    } else {
        float* fvec = ws;
        float* gvec = ws + Bn * 64;
        float* fb   = ws + 2 * Bn * 64;
        float* gb   = fb + Bn;
        if (!bwd) { fvec[b * 64 + j] = q; if (j == 0) fb[b] = base; }
        else      { gvec[b * 64 + j] = q; if (j == 0) gb[b] = base; }
    }
}

// ---------------------------------------------------------------------------
// Kernel 3: combine halves: logZ = log(f . g) + fbase + gbase; out[b] -= logZ
// ---------------------------------------------------------------------------
__global__ __launch_bounds__(64, 1) void crf_combine(
    const float* __restrict__ ws, float* __restrict__ out)
{
    const int b = blockIdx.x;
    const int j = threadIdx.x;
    const float* fvec = ws;
    const float* gvec = ws + Bn * 64;
    const float* fb   = ws + 2 * Bn * 64;
    const float* gb   = fb + Bn;

    float p = wave_sum(fvec[b * 64 + j] * gvec[b * 64 + j]);
    if (j == 0) out[b] -= (__logf(p) + fb[b] + gb[b]);
}

extern "C" void kernel_launch(void* const* d_in, const int* in_sizes, int n_in,
                              void* d_out, int out_size, void* d_ws, size_t ws_size,
                              hipStream_t stream) {
    const float* inputs = (const float*)d_in[0];
    const float* trans  = (const float*)d_in[1];
    const int*   tags   = (const int*)d_in[2];
    const int*   lens   = (const int*)d_in[3];
    float* out = (float*)d_out;
    float* ws  = (float*)d_ws;

    crf_scores<<<Bn, 256, 0, stream>>>(inputs, trans, tags, lens, out);

    const size_t need = (size_t)(2 * Bn * 64 + 2 * Bn) * sizeof(float);
    if (ws_size >= need) {
        crf_fwdbwd<false><<<2 * Bn, 64, 0, stream>>>(inputs, trans, lens, ws, out);
        crf_combine<<<Bn, 64, 0, stream>>>(ws, out);
    } else {
        // workspace too small: single-direction fallback (slower, no ws needed)
        crf_fwdbwd<true><<<Bn, 64, 0, stream>>>(inputs, trans, lens, ws, out);
    }
}

// Round 5
// 305.261 us; speedup vs baseline: 1.2743x; 1.0256x over previous
//
#include <hip/hip_runtime.h>
#include <math.h>

#define Bn 512
#define Tn 1024
#define Nn 64
#define LOG2E_F 1.44269504088896340736f
#define LN2_F   0.69314718055994530942f

__device__ __forceinline__ float wave_max(float v) {
    #pragma unroll
    for (int o = 32; o > 0; o >>= 1) v = fmaxf(v, __shfl_xor(v, o));
    return v;
}
__device__ __forceinline__ float wave_sum(float v) {
    #pragma unroll
    for (int o = 32; o > 0; o >>= 1) v += __shfl_xor(v, o);
    return v;
}

// Cross-half exchange w[lane] -> w[lane^32] on the VALU pipe (permlane32_swap)
// instead of ds_bpermute (~100+ cyc LDS round trip). Orientation-immune: the
// returned pair is {w[l], w[l^32]} in some order; pick the one != own bits.
// (If w[l]==w[l^32] bitwise, either pick is correct.)
#if __has_builtin(__builtin_amdgcn_permlane32_swap)
__device__ __forceinline__ float xhalf32(float w) {
    typedef unsigned uint2v __attribute__((ext_vector_type(2)));
    unsigned wu = __float_as_uint(w);
    uint2v r = __builtin_amdgcn_permlane32_swap(wu, wu, false, false);
    unsigned c = (r[0] == wu) ? r[1] : r[0];
    return __uint_as_float(c);
}
#else
__device__ __forceinline__ float xhalf32(float w) { return __shfl_xor(w, 32); }
#endif

// ---------------------------------------------------------------------------
// Kernel 1: unary + binary scores -> out[b]
// ---------------------------------------------------------------------------
__global__ __launch_bounds__(256) void crf_scores(
    const float* __restrict__ inputs, const float* __restrict__ trans,
    const int* __restrict__ tags, const int* __restrict__ lens,
    float* __restrict__ out)
{
    const int b = blockIdx.x;
    const int L = lens[b];
    const int* tagb = tags + b * Tn;
    const float* inb = inputs + (size_t)b * Tn * Nn;

    float acc = 0.f;
    for (int t = threadIdx.x; t < L; t += 256) {
        int tg = tagb[t];
        acc += inb[t * Nn + tg];
        if (t >= 1) acc += trans[tagb[t - 1] * Nn + tg];
    }
    acc = wave_sum(acc);
    __shared__ float red[4];
    if ((threadIdx.x & 63) == 0) red[threadIdx.x >> 6] = acc;
    __syncthreads();
    if (threadIdx.x == 0) out[b] = (red[0] + red[1]) + (red[2] + red[3]);
}

// ---------------------------------------------------------------------------
// Kernel 2: forward/backward halves of the linear recursion in exp-space.
//   fwd: q'_o = ex_o * sum_i q_i E[i][o]
//   bwd: q'_o = sum_i (ex*q)_i E[o][i]
//
// Serial-chain budget (R4 counters: 687 cyc/step, VALUBusy 24%):
//   ds_write->ds_read data  ~140
//   8x ds_read_b128 pipe    ~100
//   64 FMA issue            ~128
//   shfl_xor(32) bpermute   ~110   <- R5 removes this (permlane32_swap, ~8)
//   mul/exp/selects/loads   ~100-200
// R5: xhalf32() replaces __shfl_xor in STEP2. Everything else unchanged.
// ---------------------------------------------------------------------------

// one recursion step; exact fp32. Single wave: LDS queue is in-order per
// wave, so write -> reads needs no barrier.
#define STEP2(BWDV, EXV) do {                                      \
    shq[j] = (BWDV) ? ((EXV) * q) : q;                             \
    float4 _qv[8];                                                 \
    _Pragma("unroll")                                              \
    for (int _cb = 0; _cb < 8; ++_cb)                              \
        _qv[_cb] = *(const float4*)&shq[(g << 5) + (_cb << 2)];    \
    float _aP0 = 0.f, _aP1 = 0.f, _aQ0 = 0.f, _aQ1 = 0.f;         \
    _Pragma("unroll")                                              \
    for (int _cb = 0; _cb < 8; _cb += 2) {                         \
        const float4 _u0 = _qv[_cb], _u1 = _qv[_cb + 1];           \
        _aP0 = fmaf(_u0.x, Ef[4*_cb + 0], _aP0);                   \
        _aQ0 = fmaf(_u0.x, Ef[32 + 4*_cb + 0], _aQ0);              \
        _aP0 = fmaf(_u0.y, Ef[4*_cb + 1], _aP0);                   \
        _aQ0 = fmaf(_u0.y, Ef[32 + 4*_cb + 1], _aQ0);              \
        _aP0 = fmaf(_u0.z, Ef[4*_cb + 2], _aP0);                   \
        _aQ0 = fmaf(_u0.z, Ef[32 + 4*_cb + 2], _aQ0);              \
        _aP0 = fmaf(_u0.w, Ef[4*_cb + 3], _aP0);                   \
        _aQ0 = fmaf(_u0.w, Ef[32 + 4*_cb + 3], _aQ0);              \
        _aP1 = fmaf(_u1.x, Ef[4*_cb + 4], _aP1);                   \
        _aQ1 = fmaf(_u1.x, Ef[32 + 4*_cb + 4], _aQ1);              \
        _aP1 = fmaf(_u1.y, Ef[4*_cb + 5], _aP1);                   \
        _aQ1 = fmaf(_u1.y, Ef[32 + 4*_cb + 5], _aQ1);              \
        _aP1 = fmaf(_u1.z, Ef[4*_cb + 6], _aP1);                   \
        _aQ1 = fmaf(_u1.z, Ef[32 + 4*_cb + 6], _aQ1);              \
        _aP1 = fmaf(_u1.w, Ef[4*_cb + 7], _aP1);                   \
        _aQ1 = fmaf(_u1.w, Ef[32 + 4*_cb + 7], _aQ1);              \
    }                                                              \
    float _aP = _aP0 + _aP1, _aQ = _aQ0 + _aQ1;                    \
    float _u = lo32 ? _aP : _aQ;                                   \
    float _w = lo32 ? _aQ : _aP;                                   \
    float _s = _u + xhalf32(_w);                                   \
    q = (BWDV) ? _s : ((EXV) * _s);                                \
} while (0)

// clamped row index: keeps every prefetch load unconditional + in-bounds
__device__ __forceinline__ int clamp_row(int tt, int Lm1) {
    return tt < 0 ? 0 : (tt > Lm1 ? Lm1 : tt);
}

template <bool FULL>
__global__ __launch_bounds__(64, 1) void crf_fwdbwd(
    const float* __restrict__ inputs, const float* __restrict__ trans,
    const int* __restrict__ lens, float* __restrict__ ws,
    float* __restrict__ out)
{
    const int j = threadIdx.x;
    const int g = j >> 5;            // input K-half this lane reads
    const int p = j & 31;
    const bool lo32 = (j < 32);
    const bool bwd = (!FULL) && (blockIdx.x >= Bn);
    const int b = bwd ? (blockIdx.x - Bn) : blockIdx.x;
    const int L = lens[b];
    const int Lm1 = L - 1;
    const float* inb = inputs + (size_t)b * Tn * Nn;

    // Ef[c]    : weight of input (g*32+c) -> output p
    // Ef[32+c] : weight of input (g*32+c) -> output p+32
    float Ef[64];
    __shared__ float trsh[64 * 65];
    __shared__ __align__(16) float shq[64];
    if (!bwd) {
        // fwd: E[i][o] = exp(trans[i*64+o])
        #pragma unroll
        for (int c = 0; c < 32; ++c) {
            Ef[c]      = exp2f(trans[(g * 32 + c) * 64 + p     ] * LOG2E_F);
            Ef[32 + c] = exp2f(trans[(g * 32 + c) * 64 + p + 32] * LOG2E_F);
        }
    } else {
        // bwd: E[o][i] = exp(trans[o*64+i]); transpose-gather via LDS
        #pragma unroll
        for (int i = 0; i < 64; ++i) trsh[i * 65 + j] = trans[i * 64 + j];
        __syncthreads();
        #pragma unroll
        for (int c = 0; c < 32; ++c) {
            Ef[c]      = exp2f(trsh[p        * 65 + g * 32 + c] * LOG2E_F);
            Ef[32 + c] = exp2f(trsh[(p + 32) * 65 + g * 32 + c] * LOG2E_F);
        }
    }

    float q, base;
    int t0, dir, n;
    const int tf = L >> 1;           // forward covers t in [1,tf], backward (tf, L-1]
    if (!bwd) {
        float x0 = inb[j];
        float m = wave_max(x0);
        q = exp2f((x0 - m) * LOG2E_F);
        base = m;
        t0 = 1; dir = 1;
        n = FULL ? (L - 1) : tf;
    } else {
        q = 1.f; base = 0.f;
        t0 = L - 1; dir = -1;
        n = (L - 1) - tf;
    }

    // current 8-row register buffer (unconditional clamped loads)
    float xc[8];
    #pragma unroll
    for (int d = 0; d < 8; ++d)
        xc[d] = inb[clamp_row(t0 + d * dir, Lm1) * Nn + j];

    int t = t0;
    int k = 0;
    float pend = 1.0f;               // deferred 1/m from previous superstep

    if (!bwd) {
        while (k + 8 <= n) {
            float xn[8];
            #pragma unroll
            for (int d = 0; d < 8; ++d)
                xn[d] = inb[clamp_row(t + (8 + d) * dir, Lm1) * Nn + j];
            float exc[8];
            #pragma unroll
            for (int u = 0; u < 8; ++u)
                exc[u] = exp2f(fmaf(xc[u], LOG2E_F, -6.0f));
            exc[2] *= pend;          // apply deferred renorm off the chain
            #pragma unroll
            for (int u = 0; u < 8; ++u) STEP2(false, exc[u]);
            float m = wave_max(q);   // latency hides under next superstep
            base += __logf(m);
            pend = 1.0f / m;
            #pragma unroll
            for (int d = 0; d < 8; ++d) xc[d] = xn[d];
            k += 8; t += 8;
        }
        q *= pend; pend = 1.0f;
        #pragma unroll
        for (int u = 0; u < 8; ++u) {
            if (k + u < n) {
                float exu = exp2f(fmaf(xc[u], LOG2E_F, -6.0f));
                STEP2(false, exu);
            }
        }
    } else {
        while (k + 8 <= n) {
            float xn[8];
            #pragma unroll
            for (int d = 0; d < 8; ++d)
                xn[d] = inb[clamp_row(t - (8 + d), Lm1) * Nn + j];
            float exc[8];
            #pragma unroll
            for (int u = 0; u < 8; ++u)
                exc[u] = exp2f(fmaf(xc[u], LOG2E_F, -6.0f));
            exc[2] *= pend;
            #pragma unroll
            for (int u = 0; u < 8; ++u) STEP2(true, exc[u]);
            float m = wave_max(q);
            base += __logf(m);
            pend = 1.0f / m;
            #pragma unroll
            for (int d = 0; d < 8; ++d) xc[d] = xn[d];
            k += 8; t -= 8;
        }
        q *= pend; pend = 1.0f;
        #pragma unroll
        for (int u = 0; u < 8; ++u) {
            if (k + u < n) {
                float exu = exp2f(fmaf(xc[u], LOG2E_F, -6.0f));
                STEP2(true, exu);
            }
        }
    }

    // final renorm + account for the per-step 1/64 scaling
    {
        float m = wave_max(q);
        q *= (1.0f / m);
        base += __logf(m) + LN2_F * 6.0f * (float)n;
    }

    if (FULL) {
        float ssum = wave_sum(q);
        if (j == 0) out[b] -= (base + __logf(ssum));
    } else {
        float* fvec = ws;
        float* gvec = ws + Bn * 64;
        float* fb   = ws + 2 * Bn * 64;
        float* gb   = fb + Bn;
        if (!bwd) { fvec[b * 64 + j] = q; if (j == 0) fb[b] = base; }
        else      { gvec[b * 64 + j] = q; if (j == 0) gb[b] = base; }
    }
}

// ---------------------------------------------------------------------------
// Kernel 3: combine halves: logZ = log(f . g) + fbase + gbase; out[b] -= logZ
// ---------------------------------------------------------------------------
__global__ __launch_bounds__(64, 1) void crf_combine(
    const float* __restrict__ ws, float* __restrict__ out)
{
    const int b = blockIdx.x;
    const int j = threadIdx.x;
    const float* fvec = ws;
    const float* gvec = ws + Bn * 64;
    const float* fb   = ws + 2 * Bn * 64;
    const float* gb   = fb + Bn;

    float p = wave_sum(fvec[b * 64 + j] * gvec[b * 64 + j]);
    if (j == 0) out[b] -= (__logf(p) + fb[b] + gb[b]);
}

extern "C" void kernel_launch(void* const* d_in, const int* in_sizes, int n_in,
                              void* d_out, int out_size, void* d_ws, size_t ws_size,
                              hipStream_t stream) {
    const float* inputs = (const float*)d_in[0];
    const float* trans  = (const float*)d_in[1];
    const int*   tags   = (const int*)d_in[2];
    const int*   lens   = (const int*)d_in[3];
    float* out = (float*)d_out;
    float* ws  = (float*)d_ws;

    crf_scores<<<Bn, 256, 0, stream>>>(inputs, trans, tags, lens, out);

    const size_t need = (size_t)(2 * Bn * 64 + 2 * Bn) * sizeof(float);
    if (ws_size >= need) {
        crf_fwdbwd<false><<<2 * Bn, 64, 0, stream>>>(inputs, trans, lens, ws, out);
        crf_combine<<<Bn, 64, 0, stream>>>(ws, out);
    } else {
        // workspace too small: single-direction fallback (slower, no ws needed)
        crf_fwdbwd<true><<<Bn, 64, 0, stream>>>(inputs, trans, lens, ws, out);
    }
}